// Round 6
// baseline (207.417 us; speedup 1.0000x reference)
//
#include <hip/hip_runtime.h>
#include <math.h>

// Problem constants
#define KJ 24
#define NV 6890
#define PREG 200
#define M_TOT (NV*3)          // 20670
#define KDIM 391              // 23*17
#define KPAD 416              // 13 chunks of 32
#define TP_STRIDE 20672       // TP/RA row stride (2 pad cols)
#define NMTILE 323            // m-tiles of 64: 323*64 = 20672

// Workspace layout (float offsets). Total 6,107,328 floats = 24.43 MB.
#define EDP_OFF 0               // 2800 E_D partials (kC grid 14 x 200)
#define EKP_OFF 2816            // 23*323 = 7429 E_K partials (kB)
#define WIP_OFF 10248           // 27 E_Wi partials
#define EWP_OFF 10280           // 27 E_W partials
#define EAP_OFF 10312           // 27 E_A partials
#define RED_OFF 10344           // 32: [0..22]=EKsum_j [23]=ED [24]=EWi [25]=EW [26]=EA
#define G_OFF   10384           // G' : 200 x 24 x 12 (16B aligned)
#define WT_OFF  67984           // W_change^T 24 x 6890
#define RA_OFF  233344          // RA 23 x 20672 (pad cols 0)
#define QBH_OFF_U 1417600       // ushort offset: qm hi bf16, 256 x 416
#define QBL_OFF_U 1524096       // ushort offset: qm lo bf16, 256 x 416
#define TP_OFF  815296          // T_p 256 x 20672 (p-major)

typedef __attribute__((ext_vector_type(8))) short short8;
typedef __attribute__((ext_vector_type(4))) float f32x4;

__constant__ int c_PARENT[24] = {0,0,0,0,1,2,3,4,5,6,7,8,9,9,9,12,13,14,16,17,18,19,20,21};
__constant__ int c_DEPTH[24]  = {0,1,1,1,2,2,2,3,3,3,4,4,4,4,4,5,5,5,6,6,7,7,8,8};
__constant__ int c_LEN[24]    = {4,3,3,3,3,3,3,3,3,2,2,2,4,3,3,2,3,3,3,3,3,3,2,2};
__constant__ int c_NBR[24][4] = {
  {0,1,2,3},{0,1,4,0},{0,2,5,0},{0,3,6,0},{1,4,7,0},{2,5,8,0},{3,6,9,0},{4,7,10,0},
  {5,8,11,0},{6,9,0,0},{7,10,0,0},{8,11,0,0},{12,13,14,15},{12,13,16,0},{12,14,17,0},
  {12,15,0,0},{13,16,18,0},{14,17,19,0},{16,18,20,0},{17,19,21,0},{18,20,22,0},
  {19,21,23,0},{20,22,0,0},{21,23,0,0}};

__device__ __forceinline__ float waveReduce(float v) {
  #pragma unroll
  for (int off = 32; off > 0; off >>= 1) v += __shfl_down(v, off, 64);
  return v;
}
__device__ __forceinline__ unsigned short f2bf(float x) {
  union { float f; unsigned u; } v; v.f = x;
  unsigned r = v.u + 0x7FFFu + ((v.u >> 16) & 1u);
  return (unsigned short)(r >> 16);
}
__device__ __forceinline__ float bf2f(unsigned short h) {
  union { unsigned u; float f; } v; v.u = ((unsigned)h) << 16; return v.f;
}

// ---- kPre: blocks 0..49 pose math (4 p/block) -> G' + qm bf16 hi/lo planes;
//      blocks 50..76: W_change^T, RA, E_Wi/E_W/E_A partials, pad zeroing ----
__global__ __launch_bounds__(256) void kPre(const float* __restrict__ J,
                                            const float* __restrict__ theta,
                                            const float* __restrict__ beta2,
                                            const float* __restrict__ Wp,
                                            const float* __restrict__ Wi,
                                            const float* __restrict__ A,
                                            float* __restrict__ ws) {
  unsigned short* qbh = (unsigned short*)ws + QBH_OFF_U;
  unsigned short* qbl = (unsigned short*)ws + QBL_OFF_U;
  int b = blockIdx.x;
  if (b < 50) {
    __shared__ float Gl[4][24][12];
    __shared__ float Gg[4][24][12];
    __shared__ float q[4][24][4];
    int w = threadIdx.x >> 6, t = threadIdx.x & 63;
    int p = b*4 + w;
    if (t < 24) {
      float x = theta[p*72 + 3*t + 0];
      float y = theta[p*72 + 3*t + 1];
      float z = theta[p*72 + 3*t + 2];
      float n2 = x*x + y*y + z*z;
      float ang = fmaxf(sqrtf(n2), 1e-8f);
      float ia = 1.f/ang;
      float ax = x*ia, ay = y*ia, az = z*ia;
      float c = cosf(ang), s = sinf(ang), C = 1.f - c;
      float jx = J[p*72+3*t], jy = J[p*72+3*t+1], jz = J[p*72+3*t+2];
      float tx = jx, ty = jy, tz = jz;
      if (t > 0) {
        int par = c_PARENT[t];
        tx -= J[p*72+3*par]; ty -= J[p*72+3*par+1]; tz -= J[p*72+3*par+2];
      }
      Gl[w][t][0]=c+C*ax*ax;   Gl[w][t][1]=C*ax*ay-s*az; Gl[w][t][2]=C*ax*az+s*ay; Gl[w][t][3]=tx;
      Gl[w][t][4]=C*ax*ay+s*az;Gl[w][t][5]=c+C*ay*ay;    Gl[w][t][6]=C*ay*az-s*ax; Gl[w][t][7]=ty;
      Gl[w][t][8]=C*ax*az-s*ay;Gl[w][t][9]=C*ay*az+s*ax; Gl[w][t][10]=c+C*az*az;   Gl[w][t][11]=tz;
      float ang2 = sqrtf(fmaxf(n2, 1e-16f));
      float inv2 = 1.f/ang2;
      float s2 = sinf(0.5f*ang2);
      q[w][t][0] = x*inv2*s2; q[w][t][1] = y*inv2*s2; q[w][t][2] = z*inv2*s2;
      q[w][t][3] = cosf(0.5f*ang2) - 1.f;
    }
    __syncthreads();
    for (int lev = 0; lev <= 8; lev++) {
      if (t < 24 && c_DEPTH[t] == lev) {
        if (lev == 0) {
          for (int i2 = 0; i2 < 12; i2++) Gg[w][0][i2] = Gl[w][0][i2];
        } else {
          int par = c_PARENT[t];
          for (int r = 0; r < 3; r++) {
            float g0 = Gg[w][par][r*4+0], g1 = Gg[w][par][r*4+1];
            float g2 = Gg[w][par][r*4+2], g3 = Gg[w][par][r*4+3];
            for (int c2 = 0; c2 < 4; c2++) {
              float v = g0*Gl[w][t][0+c2] + g1*Gl[w][t][4+c2] + g2*Gl[w][t][8+c2];
              if (c2 == 3) v += g3;
              Gg[w][t][r*4+c2] = v;
            }
          }
        }
      }
      __syncthreads();
    }
    if (t < 24) {
      float jx = J[p*72+3*t], jy = J[p*72+3*t+1], jz = J[p*72+3*t+2];
      float* gp = ws + G_OFF + p*288 + t*12;
      #pragma unroll
      for (int r = 0; r < 3; r++) {
        float off = Gg[w][t][r*4+0]*jx + Gg[w][t][r*4+1]*jy + Gg[w][t][r*4+2]*jz;
        Gg[w][t][r*4+3] -= off;
      }
      #pragma unroll
      for (int i2 = 0; i2 < 12; i2++) gp[i2] = Gg[w][t][i2];
    }
    __syncthreads();
    float b2 = beta2[0];
    for (int e = t; e < KDIM; e += 64) {
      int j = e / 17, l = e - 17*j;
      int k = j + 1;
      float val = 0.f;
      if (l < 4*c_LEN[j] + 1) {
        if (l < 16) {
          int sidx = l >> 2, cc = l & 3;
          if (sidx < c_LEN[k]) val = q[w][c_NBR[k][sidx]][cc];
        }
        if (l == 4*c_LEN[k]) val += b2;
      }
      unsigned short hi = f2bf(val);
      unsigned short lo = f2bf(val - bf2f(hi));
      qbh[p*KPAD + e] = hi;
      qbl[p*KPAD + e] = lo;
    }
    for (int e = KDIM + t; e < KPAD; e += 64) {   // k pad
      qbh[p*KPAD + e] = 0; qbl[p*KPAD + e] = 0;
    }
  } else {
    int d = b - 50;                        // 0..26
    int t = threadIdx.x;
    int n = d*256 + t;
    float ewi = 0.f, ew = 0.f, ea = 0.f;
    if (n < NV) {
      float wv[24]; float sum = 0.f;
      const float4* wp4 = (const float4*)(Wp + n*24);
      #pragma unroll
      for (int i = 0; i < 6; i++) {
        float4 v4 = wp4[i];
        wv[4*i+0] = fmaxf(v4.x, 0.f); wv[4*i+1] = fmaxf(v4.y, 0.f);
        wv[4*i+2] = fmaxf(v4.z, 0.f); wv[4*i+3] = fmaxf(v4.w, 0.f);
        sum += wv[4*i+0]+wv[4*i+1]+wv[4*i+2]+wv[4*i+3];
      }
      float inv = 1.f/(sum + 1e-8f);
      #pragma unroll
      for (int k = 0; k < 24; k++) {
        float wc = wv[k]*inv;
        ws[WT_OFF + k*NV + n] = wc;
        ew += fabsf(wc);
        float dd = wc - Wi[n*24+k];
        ewi += dd*dd;
      }
    }
    for (int i = d*256 + t; i < 23*NV; i += 27*256) ea += fabsf(A[i]);
    // RA[j][m] = relu(A[j][m/3]), pad cols 0
    for (int i = d*256 + t; i < 23*TP_STRIDE; i += 27*256) {
      int j = i / TP_STRIDE, m = i - j*TP_STRIDE;
      float v = 0.f;
      if (m < M_TOT) v = fmaxf(A[j*NV + m/3], 0.f);
      ws[RA_OFF + i] = v;
    }
    // zero qm bf16 pad rows p = 200..255
    for (int i = d*256 + t; i < 56*KPAD; i += 27*256) {
      qbh[200*KPAD + i] = 0; qbl[200*KPAD + i] = 0;
    }
    __shared__ float red[3][4];
    int lane = t & 63, wv2 = t >> 6;
    ewi = waveReduce(ewi); ew = waveReduce(ew); ea = waveReduce(ea);
    if (lane == 0) { red[0][wv2] = ewi; red[1][wv2] = ew; red[2][wv2] = ea; }
    __syncthreads();
    if (t == 0) {
      ws[WIP_OFF + d] = red[0][0]+red[0][1]+red[0][2]+red[0][3];
      ws[EWP_OFF + d] = red[1][0]+red[1][1]+red[1][2]+red[1][3];
      ws[EAP_OFF + d] = red[2][0]+red[2][1]+red[2][2]+red[2][3];
    }
  }
}

// ---- kB v3: TP(256 x 20672) = qm(256x391) @ (K ⊙ RA)(391x20672)
//      Split-bf16 MFMA. ONE block covers all 256 p x 64 m (grid = 323):
//      K fetched once, 48 MFMA/wave per staging round (4x v2).
//      LDS B tile: row stride 40 shorts (20 dwords) -> ds_read_b128 16B-aligned,
//      read pattern covers all 32 banks (bandwidth-optimal 8-way for 1KB/instr). ----
__global__ __launch_bounds__(256, 2) void kB(const float* __restrict__ K,
                                             float* __restrict__ ws) {
  __shared__ unsigned short Bh[64*40];
  __shared__ unsigned short Bl[64*40];
  __shared__ float ek[23];
  const unsigned short* qbh = (const unsigned short*)ws + QBH_OFF_U;
  const unsigned short* qbl = (const unsigned short*)ws + QBL_OFF_U;
  float* __restrict__ TP = ws + TP_OFF;

  const int tid = threadIdx.x;
  const int bx = blockIdx.x;                 // m-tile
  const int m0 = bx * 64;
  const int w = tid >> 6, lane = tid & 63;
  const int r = lane & 15, qd = lane >> 4;   // MFMA col (m) and quad
  const int c4 = tid & 15, pr = tid >> 4;    // staging: m-quad, k-pair

  if (tid < 23) ek[tid] = 0.f;

  f32x4 acc[4][4];                           // [h: p-subtile][f: m-frag]
  #pragma unroll
  for (int h = 0; h < 4; h++)
    #pragma unroll
    for (int f = 0; f < 4; f++) acc[h][f] = (f32x4){0.f,0.f,0.f,0.f};

  // A-row offsets (ushort units): wave w owns p-rows w*64 .. w*64+63
  int aoff[4];
  #pragma unroll
  for (int h = 0; h < 4; h++) aoff[h] = (w*64 + h*16 + r) * KPAD + qd * 8;

  float wa[4], wb[4], sq0, sq1; int kg0, kg1;

  auto load_stage = [&](int ks) {
    int mm = m0 + 4*c4;
    kg0 = ks*32 + 2*pr; kg1 = kg0 + 1;
    float ka[4] = {0,0,0,0}, kc[4] = {0,0,0,0};
    sq0 = 0.f; sq1 = 0.f;
    #pragma unroll
    for (int i = 0; i < 4; i++) { wa[i] = 0.f; wb[i] = 0.f; }
    if (kg0 < KDIM) {
      int j = kg0 / 17;
      const float* kr = K + (size_t)kg0*M_TOT + mm;
      if (mm + 3 < M_TOT) {
        float2 x = *(const float2*)kr; float2 y = *(const float2*)(kr+2);
        ka[0]=x.x; ka[1]=x.y; ka[2]=y.x; ka[3]=y.y;
      } else {
        #pragma unroll
        for (int i = 0; i < 4; i++) if (mm+i < M_TOT) ka[i] = kr[i];
      }
      float4 ra = *(const float4*)(ws + RA_OFF + (size_t)j*TP_STRIDE + mm);
      wa[0]=ka[0]*ra.x; wa[1]=ka[1]*ra.y; wa[2]=ka[2]*ra.z; wa[3]=ka[3]*ra.w;
      sq0 = ka[0]*ka[0]+ka[1]*ka[1]+ka[2]*ka[2]+ka[3]*ka[3];
    }
    if (kg1 < KDIM) {
      int j = kg1 / 17;
      const float* kr = K + (size_t)kg1*M_TOT + mm;
      if (mm + 3 < M_TOT) {
        float2 x = *(const float2*)kr; float2 y = *(const float2*)(kr+2);
        kc[0]=x.x; kc[1]=x.y; kc[2]=y.x; kc[3]=y.y;
      } else {
        #pragma unroll
        for (int i = 0; i < 4; i++) if (mm+i < M_TOT) kc[i] = kr[i];
      }
      float4 ra = *(const float4*)(ws + RA_OFF + (size_t)j*TP_STRIDE + mm);
      wb[0]=kc[0]*ra.x; wb[1]=kc[1]*ra.y; wb[2]=kc[2]*ra.z; wb[3]=kc[3]*ra.w;
      sq1 = kc[0]*kc[0]+kc[1]*kc[1]+kc[2]*kc[2]+kc[3]*kc[3];
    }
  };
  auto write_stage = [&]() {
    #pragma unroll
    for (int i = 0; i < 4; i++) {
      unsigned short h0 = f2bf(wa[i]); unsigned short l0 = f2bf(wa[i] - bf2f(h0));
      unsigned short h1 = f2bf(wb[i]); unsigned short l1 = f2bf(wb[i] - bf2f(h1));
      int mi = 4*c4 + i;
      *(unsigned*)&Bh[mi*40 + pr*2] = (unsigned)h0 | ((unsigned)h1 << 16);
      *(unsigned*)&Bl[mi*40 + pr*2] = (unsigned)l0 | ((unsigned)l1 << 16);
    }
    // E_K: reduce raw K^2 over the 16 m-lanes sharing this k-pair
    #pragma unroll
    for (int off = 1; off <= 8; off <<= 1) {
      sq0 += __shfl_xor(sq0, off, 64);
      sq1 += __shfl_xor(sq1, off, 64);
    }
    if ((lane & 15) == 0) {
      if (kg0 < KDIM) atomicAdd(&ek[kg0/17], sq0);
      if (kg1 < KDIM) atomicAdd(&ek[kg1/17], sq1);
    }
  };

  load_stage(0);
  for (int ks = 0; ks < 13; ks++) {
    __syncthreads();                    // prior compute done with LDS (and ek init)
    write_stage();
    if (ks + 1 < 13) load_stage(ks + 1);
    __syncthreads();
    int kso = ks * 32;
    short8 ah[4], al[4];
    #pragma unroll
    for (int h = 0; h < 4; h++) {
      ah[h] = *(const short8*)(qbh + aoff[h] + kso);
      al[h] = *(const short8*)(qbl + aoff[h] + kso);
    }
    #pragma unroll
    for (int f = 0; f < 4; f++) {
      int m = f*16 + r;
      short8 bh = *(const short8*)(&Bh[m*40 + qd*8]);
      short8 bl = *(const short8*)(&Bl[m*40 + qd*8]);
      #pragma unroll
      for (int h = 0; h < 4; h++) {
        acc[h][f] = __builtin_amdgcn_mfma_f32_16x16x32_bf16(ah[h], bh, acc[h][f], 0, 0, 0);
        acc[h][f] = __builtin_amdgcn_mfma_f32_16x16x32_bf16(ah[h], bl, acc[h][f], 0, 0, 0);
        acc[h][f] = __builtin_amdgcn_mfma_f32_16x16x32_bf16(al[h], bh, acc[h][f], 0, 0, 0);
      }
    }
  }
  // epilogue: C layout col=lane&15 (m), row=quad*4+reg (p)
  #pragma unroll
  for (int h = 0; h < 4; h++)
    #pragma unroll
    for (int f = 0; f < 4; f++)
      #pragma unroll
      for (int g = 0; g < 4; g++) {
        int p = w*64 + h*16 + qd*4 + g;
        TP[(size_t)p*TP_STRIDE + m0 + f*16 + r] = acc[h][f][g];
      }
  __syncthreads();
  if (tid < 23)
    ws[EKP_OFF + tid*NMTILE + bx] = ek[tid];
}

// ---- kC: skinning + verts + E_D. 2 verts/thread, 1 p/block, grid (14,200). ----
__global__ __launch_bounds__(256) void kC(const float* __restrict__ V,
                                          const float* __restrict__ T,
                                          float* __restrict__ ws,
                                          float* __restrict__ out) {
  int p = blockIdx.y;
  int n0 = (blockIdx.x*256 + threadIdx.x) * 2;
  __shared__ float Gs[288];
  __shared__ float tmp[4];
  if (threadIdx.x < 72)
    ((float4*)Gs)[threadIdx.x] = ((const float4*)(ws + G_OFF + p*288))[threadIdx.x];
  __syncthreads();
  float ed = 0.f;
  if (n0 < NV) {   // NV even -> n0+1 also valid
    float M0[12], M1[12];
    #pragma unroll
    for (int i = 0; i < 12; i++) { M0[i] = 0.f; M1[i] = 0.f; }
    const float* Wt = ws + WT_OFF;
    #pragma unroll
    for (int k = 0; k < 24; k++) {
      float2 wv = *(const float2*)(Wt + k*NV + n0);   // coalesced 8B/lane
      float4 g0 = *(const float4*)(Gs + k*12 + 0);    // wave-uniform broadcast
      float4 g1 = *(const float4*)(Gs + k*12 + 4);
      float4 g2 = *(const float4*)(Gs + k*12 + 8);
      M0[0] = fmaf(wv.x, g0.x, M0[0]); M0[1]  = fmaf(wv.x, g0.y, M0[1]);
      M0[2] = fmaf(wv.x, g0.z, M0[2]); M0[3]  = fmaf(wv.x, g0.w, M0[3]);
      M0[4] = fmaf(wv.x, g1.x, M0[4]); M0[5]  = fmaf(wv.x, g1.y, M0[5]);
      M0[6] = fmaf(wv.x, g1.z, M0[6]); M0[7]  = fmaf(wv.x, g1.w, M0[7]);
      M0[8] = fmaf(wv.x, g2.x, M0[8]); M0[9]  = fmaf(wv.x, g2.y, M0[9]);
      M0[10]= fmaf(wv.x, g2.z, M0[10]);M0[11] = fmaf(wv.x, g2.w, M0[11]);
      M1[0] = fmaf(wv.y, g0.x, M1[0]); M1[1]  = fmaf(wv.y, g0.y, M1[1]);
      M1[2] = fmaf(wv.y, g0.z, M1[2]); M1[3]  = fmaf(wv.y, g0.w, M1[3]);
      M1[4] = fmaf(wv.y, g1.x, M1[4]); M1[5]  = fmaf(wv.y, g1.y, M1[5]);
      M1[6] = fmaf(wv.y, g1.z, M1[6]); M1[7]  = fmaf(wv.y, g1.w, M1[7]);
      M1[8] = fmaf(wv.y, g2.x, M1[8]); M1[9]  = fmaf(wv.y, g2.y, M1[9]);
      M1[10]= fmaf(wv.y, g2.z, M1[10]);M1[11] = fmaf(wv.y, g2.w, M1[11]);
    }
    size_t tb = (size_t)p*M_TOT + 3*n0;       // T, V, out base (8B aligned)
    size_t pb = (size_t)p*TP_STRIDE + 3*n0;   // TP base (8B aligned)
    float2 q0 = *(const float2*)(ws + TP_OFF + pb);
    float2 q1 = *(const float2*)(ws + TP_OFF + pb + 2);
    float2 q2 = *(const float2*)(ws + TP_OFF + pb + 4);
    float2 s0 = *(const float2*)(T + tb);
    float2 s1 = *(const float2*)(T + tb + 2);
    float2 s2 = *(const float2*)(T + tb + 4);
    float ta0 = q0.x + s0.x, ta1 = q0.y + s0.y, ta2 = q1.x + s1.x;
    float tb0 = q1.y + s1.y, tb1 = q2.x + s2.x, tb2 = q2.y + s2.y;
    float v00 = M0[0]*ta0 + M0[1]*ta1 + M0[2]*ta2  + M0[3];
    float v01 = M0[4]*ta0 + M0[5]*ta1 + M0[6]*ta2  + M0[7];
    float v02 = M0[8]*ta0 + M0[9]*ta1 + M0[10]*ta2 + M0[11];
    float v10 = M1[0]*tb0 + M1[1]*tb1 + M1[2]*tb2  + M1[3];
    float v11 = M1[4]*tb0 + M1[5]*tb1 + M1[6]*tb2  + M1[7];
    float v12 = M1[8]*tb0 + M1[9]*tb1 + M1[10]*tb2 + M1[11];
    out[1+tb+0] = v00; out[1+tb+1] = v01; out[1+tb+2] = v02;
    out[1+tb+3] = v10; out[1+tb+4] = v11; out[1+tb+5] = v12;
    float2 x0 = *(const float2*)(V + tb);
    float2 x1 = *(const float2*)(V + tb + 2);
    float2 x2 = *(const float2*)(V + tb + 4);
    float d0 = x0.x-v00, d1 = x0.y-v01, d2 = x1.x-v02;
    float d3 = x1.y-v10, d4 = x2.x-v11, d5 = x2.y-v12;
    ed = d0*d0 + d1*d1 + d2*d2 + d3*d3 + d4*d4 + d5*d5;
  }
  ed = waveReduce(ed);
  int lane = threadIdx.x & 63, w = threadIdx.x >> 6;
  if (lane == 0) tmp[w] = ed;
  __syncthreads();
  if (threadIdx.x == 0)
    ws[EDP_OFF + blockIdx.y*14 + blockIdx.x] = tmp[0]+tmp[1]+tmp[2]+tmp[3];
}

// ---- kF1: parallel partial reductions (25 blocks) ----
__global__ __launch_bounds__(256) void kF1(float* __restrict__ ws) {
  __shared__ float sb[4];
  int b = blockIdx.x, t = threadIdx.x, lane = t & 63, w = t >> 6;
  if (b < 23) {                       // E_K slice sums
    float s = 0.f;
    for (int i = t; i < NMTILE; i += 256) s += ws[EKP_OFF + b*NMTILE + i];
    s = waveReduce(s);
    if (lane == 0) sb[w] = s;
    __syncthreads();
    if (t == 0) ws[RED_OFF + b] = sb[0]+sb[1]+sb[2]+sb[3];
  } else if (b == 23) {               // E_D
    float s = 0.f;
    for (int i = t; i < 2800; i += 256) s += ws[EDP_OFF + i];
    s = waveReduce(s);
    if (lane == 0) sb[w] = s;
    __syncthreads();
    if (t == 0) ws[RED_OFF + 23] = sb[0]+sb[1]+sb[2]+sb[3];
  } else {                            // E_Wi / E_W / E_A (27 partials each)
    if (w == 0) {
      float s = (lane < 27) ? ws[WIP_OFF + lane] : 0.f;
      s = waveReduce(s);
      if (lane == 0) ws[RED_OFF + 24] = s;
    } else if (w == 1) {
      float s = (lane < 27) ? ws[EWP_OFF + lane] : 0.f;
      s = waveReduce(s);
      if (lane == 0) ws[RED_OFF + 25] = s;
    } else if (w == 2) {
      float s = (lane < 27) ? ws[EAP_OFF + lane] : 0.f;
      s = waveReduce(s);
      if (lane == 0) ws[RED_OFF + 26] = s;
    }
  }
}

// ---- kF2: final combine ----
__global__ void kF2(const int* __restrict__ epoch, const float* __restrict__ ws,
                    float* __restrict__ out) {
  int t = threadIdx.x;
  float s = (t < 23) ? sqrtf(ws[RED_OFF + t]) : 0.f;
  s = waveReduce(s);
  if (t == 0) {
    float e    = (float)epoch[0];
    float g_wi = 0.1f   * expf(-0.1f  * e);
    float g_w  = 0.002f * expf(-0.008f* e);
    float g_a  = 0.001f * expf(-0.008f* e);
    float g_k  = 0.1f   * expf(-0.008f* e);
    out[0] = ws[RED_OFF+23] + g_wi*ws[RED_OFF+24] + g_w*ws[RED_OFF+25]
           + g_a*ws[RED_OFF+26] + g_k*s;
  }
}

extern "C" void kernel_launch(void* const* d_in, const int* in_sizes, int n_in,
                              void* d_out, int out_size, void* d_ws, size_t ws_size,
                              hipStream_t stream) {
  const float* V     = (const float*)d_in[0];
  const float* T     = (const float*)d_in[1];
  const float* J     = (const float*)d_in[2];
  const float* theta = (const float*)d_in[3];
  const float* Wp    = (const float*)d_in[4];
  const float* Wi    = (const float*)d_in[5];
  const float* A     = (const float*)d_in[6];
  const float* K     = (const float*)d_in[7];
  const float* b2    = (const float*)d_in[8];
  const int*   epoch = (const int*)d_in[9];
  float* out = (float*)d_out;
  float* ws  = (float*)d_ws;
  // needs ~24.5 MB workspace

  hipLaunchKernelGGL(kPre, dim3(77),       dim3(256), 0, stream,
                     J, theta, b2, Wp, Wi, A, ws);
  hipLaunchKernelGGL(kB,   dim3(NMTILE),   dim3(256), 0, stream, K, ws);
  hipLaunchKernelGGL(kC,   dim3(14, PREG), dim3(256), 0, stream, V, T, ws, out);
  hipLaunchKernelGGL(kF1,  dim3(25),       dim3(256), 0, stream, ws);
  hipLaunchKernelGGL(kF2,  dim3(1),        dim3(64),  0, stream, epoch, ws, out);
}

// Round 7
// 201.933 us; speedup vs baseline: 1.0272x; 1.0272x over previous
//
#include <hip/hip_runtime.h>
#include <math.h>

// Problem constants
#define KJ 24
#define NV 6890
#define PREG 200
#define M_TOT (NV*3)          // 20670
#define KDIM 391              // 23*17
#define KPAD 416              // 13 chunks of 32
#define TP_STRIDE 20672       // TP row stride (2 pad cols)
#define NMT64 323             // 64-wide m-tiles (kStage)
#define NSTAGE (NMT64*13)     // 4199 stage blocks
#define NMT32 646             // 32-wide m-tiles (kB)

// Workspace layout (float offsets unless _U = ushort offsets). ~54 MB total.
#define EDP_OFF 0               // 5400 E_D partials (kC 27 x 200)
#define EKP_OFF 5400            // 23*4199 = 96,577 E_K partials (kStage)
#define WIP_OFF 101984          // 27 E_Wi partials
#define EWP_OFF 102016          // 27 E_W partials
#define EAP_OFF 102048          // 27 E_A partials
#define RED_OFF 102080          // 32 final partials
#define G_OFF   102112          // G' : 200 x 24 x 12
#define TP_OFF  159712          // T_p 256 x 20672 (p-major)
#define QBH_OFF_U 10903488      // qm hi bf16, 256 x 416
#define QBL_OFF_U 11009984      // qm lo bf16, 256 x 416
#define BTH_OFF_U 11116480      // Bt hi bf16, 20672 x 416 (m-major!)
#define BTL_OFF_U 19716032      // Bt lo bf16, 20672 x 416

typedef __attribute__((ext_vector_type(8))) short short8;
typedef __attribute__((ext_vector_type(4))) float f32x4;
typedef __attribute__((ext_vector_type(4))) unsigned int u32x4;

__constant__ int c_PARENT[24] = {0,0,0,0,1,2,3,4,5,6,7,8,9,9,9,12,13,14,16,17,18,19,20,21};
__constant__ int c_DEPTH[24]  = {0,1,1,1,2,2,2,3,3,3,4,4,4,4,4,5,5,5,6,6,7,7,8,8};
__constant__ int c_LEN[24]    = {4,3,3,3,3,3,3,3,3,2,2,2,4,3,3,2,3,3,3,3,3,3,2,2};
__constant__ int c_NBR[24][4] = {
  {0,1,2,3},{0,1,4,0},{0,2,5,0},{0,3,6,0},{1,4,7,0},{2,5,8,0},{3,6,9,0},{4,7,10,0},
  {5,8,11,0},{6,9,0,0},{7,10,0,0},{8,11,0,0},{12,13,14,15},{12,13,16,0},{12,14,17,0},
  {12,15,0,0},{13,16,18,0},{14,17,19,0},{16,18,20,0},{17,19,21,0},{18,20,22,0},
  {19,21,23,0},{20,22,0,0},{21,23,0,0}};

__device__ __forceinline__ float waveReduce(float v) {
  #pragma unroll
  for (int off = 32; off > 0; off >>= 1) v += __shfl_down(v, off, 64);
  return v;
}
__device__ __forceinline__ unsigned short f2bf(float x) {
  union { float f; unsigned u; } v; v.f = x;
  unsigned r = v.u + 0x7FFFu + ((v.u >> 16) & 1u);
  return (unsigned short)(r >> 16);
}
__device__ __forceinline__ float bf2f(unsigned short h) {
  union { unsigned u; float f; } v; v.u = ((unsigned)h) << 16; return v.f;
}

// ---- kPre: b<50: pose math (4 p/block) -> G' + qm bf16 hi/lo planes
//            b<77: E_Wi/E_W/E_A partials + qm pad-row zeroing
//            else: kStage — Bt[m][k] = bf16-split(K ⊙ reluA) transpose + E_K ----
__global__ __launch_bounds__(256) void kPre(const float* __restrict__ J,
                                            const float* __restrict__ theta,
                                            const float* __restrict__ beta2,
                                            const float* __restrict__ Wp,
                                            const float* __restrict__ Wi,
                                            const float* __restrict__ A,
                                            const float* __restrict__ K,
                                            float* __restrict__ ws) {
  unsigned short* qbh = (unsigned short*)ws + QBH_OFF_U;
  unsigned short* qbl = (unsigned short*)ws + QBL_OFF_U;
  int b = blockIdx.x;
  if (b < 50) {
    __shared__ float Gl[4][24][12];
    __shared__ float Gg[4][24][12];
    __shared__ float q[4][24][4];
    int w = threadIdx.x >> 6, t = threadIdx.x & 63;
    int p = b*4 + w;
    if (t < 24) {
      float x = theta[p*72 + 3*t + 0];
      float y = theta[p*72 + 3*t + 1];
      float z = theta[p*72 + 3*t + 2];
      float n2 = x*x + y*y + z*z;
      float ang = fmaxf(sqrtf(n2), 1e-8f);
      float ia = 1.f/ang;
      float ax = x*ia, ay = y*ia, az = z*ia;
      float c = cosf(ang), s = sinf(ang), C = 1.f - c;
      float jx = J[p*72+3*t], jy = J[p*72+3*t+1], jz = J[p*72+3*t+2];
      float tx = jx, ty = jy, tz = jz;
      if (t > 0) {
        int par = c_PARENT[t];
        tx -= J[p*72+3*par]; ty -= J[p*72+3*par+1]; tz -= J[p*72+3*par+2];
      }
      Gl[w][t][0]=c+C*ax*ax;   Gl[w][t][1]=C*ax*ay-s*az; Gl[w][t][2]=C*ax*az+s*ay; Gl[w][t][3]=tx;
      Gl[w][t][4]=C*ax*ay+s*az;Gl[w][t][5]=c+C*ay*ay;    Gl[w][t][6]=C*ay*az-s*ax; Gl[w][t][7]=ty;
      Gl[w][t][8]=C*ax*az-s*ay;Gl[w][t][9]=C*ay*az+s*ax; Gl[w][t][10]=c+C*az*az;   Gl[w][t][11]=tz;
      float ang2 = sqrtf(fmaxf(n2, 1e-16f));
      float inv2 = 1.f/ang2;
      float s2 = sinf(0.5f*ang2);
      q[w][t][0] = x*inv2*s2; q[w][t][1] = y*inv2*s2; q[w][t][2] = z*inv2*s2;
      q[w][t][3] = cosf(0.5f*ang2) - 1.f;
    }
    __syncthreads();
    for (int lev = 0; lev <= 8; lev++) {
      if (t < 24 && c_DEPTH[t] == lev) {
        if (lev == 0) {
          for (int i2 = 0; i2 < 12; i2++) Gg[w][0][i2] = Gl[w][0][i2];
        } else {
          int par = c_PARENT[t];
          for (int r = 0; r < 3; r++) {
            float g0 = Gg[w][par][r*4+0], g1 = Gg[w][par][r*4+1];
            float g2 = Gg[w][par][r*4+2], g3 = Gg[w][par][r*4+3];
            for (int c2 = 0; c2 < 4; c2++) {
              float v = g0*Gl[w][t][0+c2] + g1*Gl[w][t][4+c2] + g2*Gl[w][t][8+c2];
              if (c2 == 3) v += g3;
              Gg[w][t][r*4+c2] = v;
            }
          }
        }
      }
      __syncthreads();
    }
    if (t < 24) {
      float jx = J[p*72+3*t], jy = J[p*72+3*t+1], jz = J[p*72+3*t+2];
      float* gp = ws + G_OFF + p*288 + t*12;
      #pragma unroll
      for (int r = 0; r < 3; r++) {
        float off = Gg[w][t][r*4+0]*jx + Gg[w][t][r*4+1]*jy + Gg[w][t][r*4+2]*jz;
        Gg[w][t][r*4+3] -= off;
      }
      #pragma unroll
      for (int i2 = 0; i2 < 12; i2++) gp[i2] = Gg[w][t][i2];
    }
    __syncthreads();
    float b2 = beta2[0];
    for (int e = t; e < KDIM; e += 64) {
      int j = e / 17, l = e - 17*j;
      int k = j + 1;
      float val = 0.f;
      if (l < 4*c_LEN[j] + 1) {
        if (l < 16) {
          int sidx = l >> 2, cc = l & 3;
          if (sidx < c_LEN[k]) val = q[w][c_NBR[k][sidx]][cc];
        }
        if (l == 4*c_LEN[k]) val += b2;
      }
      unsigned short hi = f2bf(val);
      unsigned short lo = f2bf(val - bf2f(hi));
      qbh[p*KPAD + e] = hi;
      qbl[p*KPAD + e] = lo;
    }
    for (int e = KDIM + t; e < KPAD; e += 64) {
      qbh[p*KPAD + e] = 0; qbl[p*KPAD + e] = 0;
    }
  } else if (b < 77) {
    int d = b - 50;                        // 0..26
    int t = threadIdx.x;
    int n = d*256 + t;
    float ewi = 0.f, ew = 0.f, ea = 0.f;
    if (n < NV) {
      float wv[24]; float sum = 0.f;
      const float4* wp4 = (const float4*)(Wp + n*24);
      #pragma unroll
      for (int i = 0; i < 6; i++) {
        float4 v4 = wp4[i];
        wv[4*i+0] = fmaxf(v4.x, 0.f); wv[4*i+1] = fmaxf(v4.y, 0.f);
        wv[4*i+2] = fmaxf(v4.z, 0.f); wv[4*i+3] = fmaxf(v4.w, 0.f);
        sum += wv[4*i+0]+wv[4*i+1]+wv[4*i+2]+wv[4*i+3];
      }
      float inv = 1.f/(sum + 1e-8f);
      #pragma unroll
      for (int k = 0; k < 24; k++) {
        float wc = wv[k]*inv;
        ew += fabsf(wc);
        float dd = wc - Wi[n*24+k];
        ewi += dd*dd;
      }
    }
    for (int i = d*256 + t; i < 23*NV; i += 27*256) ea += fabsf(A[i]);
    // zero qm bf16 pad rows p = 200..255
    for (int i = d*256 + t; i < 56*KPAD; i += 27*256) {
      qbh[200*KPAD + i] = 0; qbl[200*KPAD + i] = 0;
    }
    __shared__ float red[3][4];
    int lane = t & 63, wv2 = t >> 6;
    ewi = waveReduce(ewi); ew = waveReduce(ew); ea = waveReduce(ea);
    if (lane == 0) { red[0][wv2] = ewi; red[1][wv2] = ew; red[2][wv2] = ea; }
    __syncthreads();
    if (t == 0) {
      ws[WIP_OFF + d] = red[0][0]+red[0][1]+red[0][2]+red[0][3];
      ws[EWP_OFF + d] = red[1][0]+red[1][1]+red[1][2]+red[1][3];
      ws[EAP_OFF + d] = red[2][0]+red[2][1]+red[2][2]+red[2][3];
    }
  } else {
    // ---------------- kStage: 64m x 32k tile transpose ----------------
    int flat = b - 77;                     // 0..4198
    int bx = flat % NMT64, by = flat / NMT64;
    int m0 = bx*64, kg0 = by*32;
    __shared__ unsigned short Sh[32*66];   // [krow][m], stride 66 (2-way-free)
    __shared__ unsigned short Sl[32*66];
    __shared__ float ek[23];
    int t = threadIdx.x;
    if (t < 23) ek[t] = 0.f;
    __syncthreads();
    int krow = t >> 3, mseg = (t & 7) * 8;
    int kg = kg0 + krow;
    int mm = m0 + mseg;
    float kv[8], wv[8]; float sq = 0.f;
    #pragma unroll
    for (int i = 0; i < 8; i++) { kv[i] = 0.f; wv[i] = 0.f; }
    if (kg < KDIM) {
      const float* kr = K + (size_t)kg*M_TOT + mm;
      if (mm + 7 < M_TOT) {
        float4 a4 = *(const float4*)kr; float4 b4 = *(const float4*)(kr+4);
        kv[0]=a4.x; kv[1]=a4.y; kv[2]=a4.z; kv[3]=a4.w;
        kv[4]=b4.x; kv[5]=b4.y; kv[6]=b4.z; kv[7]=b4.w;
      } else {
        #pragma unroll
        for (int i = 0; i < 8; i++) if (mm+i < M_TOT) kv[i] = kr[i];
      }
      int j = kg / 17;
      #pragma unroll
      for (int i = 0; i < 8; i++) {
        float av = (mm+i < M_TOT) ? fmaxf(A[j*NV + (mm+i)/3], 0.f) : 0.f;
        wv[i] = kv[i]*av;
        sq = fmaf(kv[i], kv[i], sq);
      }
    }
    #pragma unroll
    for (int c = 0; c < 4; c++) {
      unsigned short h0 = f2bf(wv[2*c]),  h1 = f2bf(wv[2*c+1]);
      unsigned short l0 = f2bf(wv[2*c]   - bf2f(h0));
      unsigned short l1 = f2bf(wv[2*c+1] - bf2f(h1));
      *(unsigned*)&Sh[krow*66 + mseg + 2*c] = (unsigned)h0 | ((unsigned)h1 << 16);
      *(unsigned*)&Sl[krow*66 + mseg + 2*c] = (unsigned)l0 | ((unsigned)l1 << 16);
    }
    sq += __shfl_xor(sq, 1, 64);
    sq += __shfl_xor(sq, 2, 64);
    sq += __shfl_xor(sq, 4, 64);
    if ((t & 7) == 0 && kg < KDIM) atomicAdd(&ek[kg/17], sq);
    __syncthreads();
    int mrow = t >> 2, kq = t & 3;
    unsigned dh[4], dl[4];
    #pragma unroll
    for (int c2 = 0; c2 < 4; c2++) {
      unsigned short s0 = Sh[(kq*8 + 2*c2    )*66 + mrow];
      unsigned short s1 = Sh[(kq*8 + 2*c2 + 1)*66 + mrow];
      dh[c2] = (unsigned)s0 | ((unsigned)s1 << 16);
      unsigned short u0 = Sl[(kq*8 + 2*c2    )*66 + mrow];
      unsigned short u1 = Sl[(kq*8 + 2*c2 + 1)*66 + mrow];
      dl[c2] = (unsigned)u0 | ((unsigned)u1 << 16);
    }
    unsigned short* BtH = (unsigned short*)ws + BTH_OFF_U;
    unsigned short* BtL = (unsigned short*)ws + BTL_OFF_U;
    size_t o = (size_t)(m0 + mrow)*KPAD + kg0 + kq*8;
    *(u32x4*)(BtH + o) = (u32x4){dh[0], dh[1], dh[2], dh[3]};
    *(u32x4*)(BtL + o) = (u32x4){dl[0], dl[1], dl[2], dl[3]};
    if (t < 23) ws[EKP_OFF + t*NSTAGE + flat] = ek[t];
  }
}

// ---- kB: barrier-free, LDS-free split-bf16 MFMA GEMM.
//      Grid 646 (m-tile 32); block 256 = 4 waves, wave w owns p 64w..64w+63.
//      A (qm) and B (Bt) pre-swizzled bf16 planes read straight into frags. ----
__global__ __launch_bounds__(256) void kB(float* __restrict__ ws) {
  const unsigned short* qbh = (const unsigned short*)ws + QBH_OFF_U;
  const unsigned short* qbl = (const unsigned short*)ws + QBL_OFF_U;
  const unsigned short* BtH = (const unsigned short*)ws + BTH_OFF_U;
  const unsigned short* BtL = (const unsigned short*)ws + BTL_OFF_U;
  float* __restrict__ TP = ws + TP_OFF;
  const int tid = threadIdx.x, bx = blockIdx.x;
  const int m0 = bx * 32;
  const int w = tid >> 6, lane = tid & 63;
  const int r = lane & 15, qd = lane >> 4;

  f32x4 acc[4][2];
  #pragma unroll
  for (int h = 0; h < 4; h++)
    #pragma unroll
    for (int f = 0; f < 2; f++) acc[h][f] = (f32x4){0.f,0.f,0.f,0.f};

  int aofs[4], bofs[2];
  #pragma unroll
  for (int h = 0; h < 4; h++) aofs[h] = (w*64 + h*16 + r)*KPAD + qd*8;
  #pragma unroll
  for (int f = 0; f < 2; f++) bofs[f] = (m0 + f*16 + r)*KPAD + qd*8;

  short8 bh[2][2], bl[2][2];
  #pragma unroll
  for (int f = 0; f < 2; f++) {
    bh[0][f] = *(const short8*)(BtH + bofs[f]);
    bl[0][f] = *(const short8*)(BtL + bofs[f]);
  }
  #pragma unroll
  for (int ks = 0; ks < 13; ks++) {
    const int cur = ks & 1, nxt = cur ^ 1;
    if (ks + 1 < 13) {
      #pragma unroll
      for (int f = 0; f < 2; f++) {
        bh[nxt][f] = *(const short8*)(BtH + bofs[f] + (ks+1)*32);
        bl[nxt][f] = *(const short8*)(BtL + bofs[f] + (ks+1)*32);
      }
    }
    short8 ah[4], al[4];
    #pragma unroll
    for (int h = 0; h < 4; h++) {
      ah[h] = *(const short8*)(qbh + aofs[h] + ks*32);
      al[h] = *(const short8*)(qbl + aofs[h] + ks*32);
    }
    #pragma unroll
    for (int f = 0; f < 2; f++)
      #pragma unroll
      for (int h = 0; h < 4; h++) {
        acc[h][f] = __builtin_amdgcn_mfma_f32_16x16x32_bf16(ah[h], bh[cur][f], acc[h][f], 0, 0, 0);
        acc[h][f] = __builtin_amdgcn_mfma_f32_16x16x32_bf16(ah[h], bl[cur][f], acc[h][f], 0, 0, 0);
        acc[h][f] = __builtin_amdgcn_mfma_f32_16x16x32_bf16(al[h], bh[cur][f], acc[h][f], 0, 0, 0);
      }
  }
  // C layout: col = lane&15 (m), row = qd*4 + g (p)
  #pragma unroll
  for (int h = 0; h < 4; h++)
    #pragma unroll
    for (int f = 0; f < 2; f++)
      #pragma unroll
      for (int g = 0; g < 4; g++) {
        int p = w*64 + h*16 + qd*4 + g;
        TP[(size_t)p*TP_STRIDE + m0 + f*16 + r] = acc[h][f][g];
      }
}

// ---- kC: skinning + verts + E_D. 1 vert/thread, w from Wp direct (6 indep float4),
//      M scaled by inv once at end. Grid (27, 200). ----
__global__ __launch_bounds__(256) void kC(const float* __restrict__ V,
                                          const float* __restrict__ T,
                                          const float* __restrict__ Wp,
                                          float* __restrict__ ws,
                                          float* __restrict__ out) {
  int p = blockIdx.y;
  int n = blockIdx.x*256 + threadIdx.x;
  __shared__ float Gs[288];
  __shared__ float tmp[4];
  if (threadIdx.x < 72)
    ((float4*)Gs)[threadIdx.x] = ((const float4*)(ws + G_OFF + p*288))[threadIdx.x];
  __syncthreads();
  float ed = 0.f;
  if (n < NV) {
    float wv[24]; float sum = 0.f;
    const float4* wp4 = (const float4*)(Wp + n*24);
    #pragma unroll
    for (int i = 0; i < 6; i++) {
      float4 v4 = wp4[i];
      wv[4*i+0] = fmaxf(v4.x, 0.f); wv[4*i+1] = fmaxf(v4.y, 0.f);
      wv[4*i+2] = fmaxf(v4.z, 0.f); wv[4*i+3] = fmaxf(v4.w, 0.f);
      sum += wv[4*i+0]+wv[4*i+1]+wv[4*i+2]+wv[4*i+3];
    }
    float inv = 1.f/(sum + 1e-8f);
    float M[12];
    #pragma unroll
    for (int i = 0; i < 12; i++) M[i] = 0.f;
    #pragma unroll
    for (int k = 0; k < 24; k++) {
      float wc = wv[k];
      float4 g0 = *(const float4*)(Gs + k*12 + 0);
      float4 g1 = *(const float4*)(Gs + k*12 + 4);
      float4 g2 = *(const float4*)(Gs + k*12 + 8);
      M[0] = fmaf(wc, g0.x, M[0]); M[1]  = fmaf(wc, g0.y, M[1]);
      M[2] = fmaf(wc, g0.z, M[2]); M[3]  = fmaf(wc, g0.w, M[3]);
      M[4] = fmaf(wc, g1.x, M[4]); M[5]  = fmaf(wc, g1.y, M[5]);
      M[6] = fmaf(wc, g1.z, M[6]); M[7]  = fmaf(wc, g1.w, M[7]);
      M[8] = fmaf(wc, g2.x, M[8]); M[9]  = fmaf(wc, g2.y, M[9]);
      M[10]= fmaf(wc, g2.z, M[10]);M[11] = fmaf(wc, g2.w, M[11]);
    }
    #pragma unroll
    for (int i = 0; i < 12; i++) M[i] *= inv;
    size_t tb = (size_t)p*M_TOT + 3*n;
    size_t pb = (size_t)p*TP_STRIDE + 3*n;
    float t0 = ws[TP_OFF + pb + 0] + T[tb + 0];
    float t1 = ws[TP_OFF + pb + 1] + T[tb + 1];
    float t2 = ws[TP_OFF + pb + 2] + T[tb + 2];
    float v0 = M[0]*t0 + M[1]*t1 + M[2]*t2  + M[3];
    float v1 = M[4]*t0 + M[5]*t1 + M[6]*t2  + M[7];
    float v2 = M[8]*t0 + M[9]*t1 + M[10]*t2 + M[11];
    out[1+tb+0] = v0; out[1+tb+1] = v1; out[1+tb+2] = v2;
    float d0 = V[tb+0]-v0, d1 = V[tb+1]-v1, d2 = V[tb+2]-v2;
    ed = d0*d0 + d1*d1 + d2*d2;
  }
  ed = waveReduce(ed);
  int lane = threadIdx.x & 63, w = threadIdx.x >> 6;
  if (lane == 0) tmp[w] = ed;
  __syncthreads();
  if (threadIdx.x == 0)
    ws[EDP_OFF + blockIdx.y*27 + blockIdx.x] = tmp[0]+tmp[1]+tmp[2]+tmp[3];
}

// ---- kF1: parallel partial reductions (25 blocks) ----
__global__ __launch_bounds__(256) void kF1(float* __restrict__ ws) {
  __shared__ float sb[4];
  int b = blockIdx.x, t = threadIdx.x, lane = t & 63, w = t >> 6;
  if (b < 23) {                       // E_K slice sums
    float s = 0.f;
    for (int i = t; i < NSTAGE; i += 256) s += ws[EKP_OFF + b*NSTAGE + i];
    s = waveReduce(s);
    if (lane == 0) sb[w] = s;
    __syncthreads();
    if (t == 0) ws[RED_OFF + b] = sb[0]+sb[1]+sb[2]+sb[3];
  } else if (b == 23) {               // E_D
    float s = 0.f;
    for (int i = t; i < 5400; i += 256) s += ws[EDP_OFF + i];
    s = waveReduce(s);
    if (lane == 0) sb[w] = s;
    __syncthreads();
    if (t == 0) ws[RED_OFF + 23] = sb[0]+sb[1]+sb[2]+sb[3];
  } else {                            // E_Wi / E_W / E_A (27 partials each)
    if (w == 0) {
      float s = (lane < 27) ? ws[WIP_OFF + lane] : 0.f;
      s = waveReduce(s);
      if (lane == 0) ws[RED_OFF + 24] = s;
    } else if (w == 1) {
      float s = (lane < 27) ? ws[EWP_OFF + lane] : 0.f;
      s = waveReduce(s);
      if (lane == 0) ws[RED_OFF + 25] = s;
    } else if (w == 2) {
      float s = (lane < 27) ? ws[EAP_OFF + lane] : 0.f;
      s = waveReduce(s);
      if (lane == 0) ws[RED_OFF + 26] = s;
    }
  }
}

// ---- kF2: final combine ----
__global__ void kF2(const int* __restrict__ epoch, const float* __restrict__ ws,
                    float* __restrict__ out) {
  int t = threadIdx.x;
  float s = (t < 23) ? sqrtf(ws[RED_OFF + t]) : 0.f;
  s = waveReduce(s);
  if (t == 0) {
    float e    = (float)epoch[0];
    float g_wi = 0.1f   * expf(-0.1f  * e);
    float g_w  = 0.002f * expf(-0.008f* e);
    float g_a  = 0.001f * expf(-0.008f* e);
    float g_k  = 0.1f   * expf(-0.008f* e);
    out[0] = ws[RED_OFF+23] + g_wi*ws[RED_OFF+24] + g_w*ws[RED_OFF+25]
           + g_a*ws[RED_OFF+26] + g_k*s;
  }
}

extern "C" void kernel_launch(void* const* d_in, const int* in_sizes, int n_in,
                              void* d_out, int out_size, void* d_ws, size_t ws_size,
                              hipStream_t stream) {
  const float* V     = (const float*)d_in[0];
  const float* T     = (const float*)d_in[1];
  const float* J     = (const float*)d_in[2];
  const float* theta = (const float*)d_in[3];
  const float* Wp    = (const float*)d_in[4];
  const float* Wi    = (const float*)d_in[5];
  const float* A     = (const float*)d_in[6];
  const float* K     = (const float*)d_in[7];
  const float* b2    = (const float*)d_in[8];
  const int*   epoch = (const int*)d_in[9];
  float* out = (float*)d_out;
  float* ws  = (float*)d_ws;
  // needs ~54 MB workspace

  hipLaunchKernelGGL(kPre, dim3(77 + NSTAGE), dim3(256), 0, stream,
                     J, theta, b2, Wp, Wi, A, K, ws);
  hipLaunchKernelGGL(kB,   dim3(NMT32),       dim3(256), 0, stream, ws);
  hipLaunchKernelGGL(kC,   dim3(27, PREG),    dim3(256), 0, stream, V, T, Wp, ws, out);
  hipLaunchKernelGGL(kF1,  dim3(25),          dim3(256), 0, stream, ws);
  hipLaunchKernelGGL(kF2,  dim3(1),           dim3(64),  0, stream, epoch, ws, out);
}

// Round 8
// 191.274 us; speedup vs baseline: 1.0844x; 1.0557x over previous
//
#include <hip/hip_runtime.h>
#include <math.h>

// Problem constants
#define KJ 24
#define NV 6890
#define PREG 200
#define M_TOT (NV*3)          // 20670
#define KDIM 391              // 23*17
#define KPAD 416              // 13 chunks of 32
#define TP_STRIDE 20672       // TP row stride (2 pad cols)
#define NMT64 323             // 64-wide m-tiles (kStage)
#define NSTAGE (NMT64*13)     // 4199 stage blocks
#define NMT32 646             // 32-wide m-tiles (kB)

// Workspace layout (float offsets unless _U = ushort offsets). ~54 MB total.
#define EDP_OFF 0               // 5400 E_D partials (kC 27 x 200)
#define EKP_OFF 5400            // 23*4199 = 96,577 E_K partials (kStage)
#define WIP_OFF 101984          // 27 E_Wi partials
#define EWP_OFF 102016          // 27 E_W partials
#define EAP_OFF 102048          // 27 E_A partials
#define RED_OFF 102080          // 32 final partials
#define G_OFF   102112          // G' : 200 x 24 x 12
#define TP_OFF  159712          // T_p 256 x 20672 (p-major)
#define QBH_OFF_U 10903488      // qm hi bf16, 256 x 416
#define QBL_OFF_U 11009984      // qm lo bf16, 256 x 416
#define BTH_OFF_U 11116480      // Bt hi bf16, 20672 x 416 (m-major)
#define BTL_OFF_U 19716032      // Bt lo bf16, 20672 x 416

typedef __attribute__((ext_vector_type(8))) short short8;
typedef __attribute__((ext_vector_type(4))) float f32x4;
typedef __attribute__((ext_vector_type(4))) unsigned int u32x4;

__constant__ int c_PARENT[24] = {0,0,0,0,1,2,3,4,5,6,7,8,9,9,9,12,13,14,16,17,18,19,20,21};
__constant__ int c_DEPTH[24]  = {0,1,1,1,2,2,2,3,3,3,4,4,4,4,4,5,5,5,6,6,7,7,8,8};
__constant__ int c_LEN[24]    = {4,3,3,3,3,3,3,3,3,2,2,2,4,3,3,2,3,3,3,3,3,3,2,2};
__constant__ int c_NBR[24][4] = {
  {0,1,2,3},{0,1,4,0},{0,2,5,0},{0,3,6,0},{1,4,7,0},{2,5,8,0},{3,6,9,0},{4,7,10,0},
  {5,8,11,0},{6,9,0,0},{7,10,0,0},{8,11,0,0},{12,13,14,15},{12,13,16,0},{12,14,17,0},
  {12,15,0,0},{13,16,18,0},{14,17,19,0},{16,18,20,0},{17,19,21,0},{18,20,22,0},
  {19,21,23,0},{20,22,0,0},{21,23,0,0}};

__device__ __forceinline__ float waveReduce(float v) {
  #pragma unroll
  for (int off = 32; off > 0; off >>= 1) v += __shfl_down(v, off, 64);
  return v;
}
__device__ __forceinline__ unsigned short f2bf(float x) {
  union { float f; unsigned u; } v; v.f = x;
  unsigned r = v.u + 0x7FFFu + ((v.u >> 16) & 1u);
  return (unsigned short)(r >> 16);
}
__device__ __forceinline__ float bf2f(unsigned short h) {
  union { unsigned u; float f; } v; v.u = ((unsigned)h) << 16; return v.f;
}

// ---- kPre: b<50: pose math (4 p/block) -> G' + qm bf16 hi/lo planes
//            b<77: E_Wi/E_W/E_A partials + qm pad-row zeroing
//            else: kStage — Bt[m][k] = bf16-split(K ⊙ reluA) transpose + E_K ----
__global__ __launch_bounds__(256) void kPre(const float* __restrict__ J,
                                            const float* __restrict__ theta,
                                            const float* __restrict__ beta2,
                                            const float* __restrict__ Wp,
                                            const float* __restrict__ Wi,
                                            const float* __restrict__ A,
                                            const float* __restrict__ K,
                                            float* __restrict__ ws) {
  unsigned short* qbh = (unsigned short*)ws + QBH_OFF_U;
  unsigned short* qbl = (unsigned short*)ws + QBL_OFF_U;
  int b = blockIdx.x;
  if (b < 50) {
    __shared__ float Gl[4][24][12];
    __shared__ float Gg[4][24][12];
    __shared__ float q[4][24][4];
    int w = threadIdx.x >> 6, t = threadIdx.x & 63;
    int p = b*4 + w;
    if (t < 24) {
      float x = theta[p*72 + 3*t + 0];
      float y = theta[p*72 + 3*t + 1];
      float z = theta[p*72 + 3*t + 2];
      float n2 = x*x + y*y + z*z;
      float ang = fmaxf(sqrtf(n2), 1e-8f);
      float ia = 1.f/ang;
      float ax = x*ia, ay = y*ia, az = z*ia;
      float c = cosf(ang), s = sinf(ang), C = 1.f - c;
      float jx = J[p*72+3*t], jy = J[p*72+3*t+1], jz = J[p*72+3*t+2];
      float tx = jx, ty = jy, tz = jz;
      if (t > 0) {
        int par = c_PARENT[t];
        tx -= J[p*72+3*par]; ty -= J[p*72+3*par+1]; tz -= J[p*72+3*par+2];
      }
      Gl[w][t][0]=c+C*ax*ax;   Gl[w][t][1]=C*ax*ay-s*az; Gl[w][t][2]=C*ax*az+s*ay; Gl[w][t][3]=tx;
      Gl[w][t][4]=C*ax*ay+s*az;Gl[w][t][5]=c+C*ay*ay;    Gl[w][t][6]=C*ay*az-s*ax; Gl[w][t][7]=ty;
      Gl[w][t][8]=C*ax*az-s*ay;Gl[w][t][9]=C*ay*az+s*ax; Gl[w][t][10]=c+C*az*az;   Gl[w][t][11]=tz;
      float ang2 = sqrtf(fmaxf(n2, 1e-16f));
      float inv2 = 1.f/ang2;
      float s2 = sinf(0.5f*ang2);
      q[w][t][0] = x*inv2*s2; q[w][t][1] = y*inv2*s2; q[w][t][2] = z*inv2*s2;
      q[w][t][3] = cosf(0.5f*ang2) - 1.f;
    }
    __syncthreads();
    for (int lev = 0; lev <= 8; lev++) {
      if (t < 24 && c_DEPTH[t] == lev) {
        if (lev == 0) {
          for (int i2 = 0; i2 < 12; i2++) Gg[w][0][i2] = Gl[w][0][i2];
        } else {
          int par = c_PARENT[t];
          for (int r = 0; r < 3; r++) {
            float g0 = Gg[w][par][r*4+0], g1 = Gg[w][par][r*4+1];
            float g2 = Gg[w][par][r*4+2], g3 = Gg[w][par][r*4+3];
            for (int c2 = 0; c2 < 4; c2++) {
              float v = g0*Gl[w][t][0+c2] + g1*Gl[w][t][4+c2] + g2*Gl[w][t][8+c2];
              if (c2 == 3) v += g3;
              Gg[w][t][r*4+c2] = v;
            }
          }
        }
      }
      __syncthreads();
    }
    if (t < 24) {
      float jx = J[p*72+3*t], jy = J[p*72+3*t+1], jz = J[p*72+3*t+2];
      float* gp = ws + G_OFF + p*288 + t*12;
      #pragma unroll
      for (int r = 0; r < 3; r++) {
        float off = Gg[w][t][r*4+0]*jx + Gg[w][t][r*4+1]*jy + Gg[w][t][r*4+2]*jz;
        Gg[w][t][r*4+3] -= off;
      }
      #pragma unroll
      for (int i2 = 0; i2 < 12; i2++) gp[i2] = Gg[w][t][i2];
    }
    __syncthreads();
    float b2 = beta2[0];
    for (int e = t; e < KDIM; e += 64) {
      int j = e / 17, l = e - 17*j;
      int k = j + 1;
      float val = 0.f;
      if (l < 4*c_LEN[j] + 1) {
        if (l < 16) {
          int sidx = l >> 2, cc = l & 3;
          if (sidx < c_LEN[k]) val = q[w][c_NBR[k][sidx]][cc];
        }
        if (l == 4*c_LEN[k]) val += b2;
      }
      unsigned short hi = f2bf(val);
      unsigned short lo = f2bf(val - bf2f(hi));
      qbh[p*KPAD + e] = hi;
      qbl[p*KPAD + e] = lo;
    }
    for (int e = KDIM + t; e < KPAD; e += 64) {
      qbh[p*KPAD + e] = 0; qbl[p*KPAD + e] = 0;
    }
  } else if (b < 77) {
    int d = b - 50;                        // 0..26
    int t = threadIdx.x;
    int n = d*256 + t;
    float ewi = 0.f, ew = 0.f, ea = 0.f;
    if (n < NV) {
      float wv[24]; float sum = 0.f;
      const float4* wp4 = (const float4*)(Wp + n*24);
      #pragma unroll
      for (int i = 0; i < 6; i++) {
        float4 v4 = wp4[i];
        wv[4*i+0] = fmaxf(v4.x, 0.f); wv[4*i+1] = fmaxf(v4.y, 0.f);
        wv[4*i+2] = fmaxf(v4.z, 0.f); wv[4*i+3] = fmaxf(v4.w, 0.f);
        sum += wv[4*i+0]+wv[4*i+1]+wv[4*i+2]+wv[4*i+3];
      }
      float inv = 1.f/(sum + 1e-8f);
      #pragma unroll
      for (int k = 0; k < 24; k++) {
        float wc = wv[k]*inv;
        ew += fabsf(wc);
        float dd = wc - Wi[n*24+k];
        ewi += dd*dd;
      }
    }
    for (int i = d*256 + t; i < 23*NV; i += 27*256) ea += fabsf(A[i]);
    for (int i = d*256 + t; i < 56*KPAD; i += 27*256) {
      qbh[200*KPAD + i] = 0; qbl[200*KPAD + i] = 0;
    }
    __shared__ float red[3][4];
    int lane = t & 63, wv2 = t >> 6;
    ewi = waveReduce(ewi); ew = waveReduce(ew); ea = waveReduce(ea);
    if (lane == 0) { red[0][wv2] = ewi; red[1][wv2] = ew; red[2][wv2] = ea; }
    __syncthreads();
    if (t == 0) {
      ws[WIP_OFF + d] = red[0][0]+red[0][1]+red[0][2]+red[0][3];
      ws[EWP_OFF + d] = red[1][0]+red[1][1]+red[1][2]+red[1][3];
      ws[EAP_OFF + d] = red[2][0]+red[2][1]+red[2][2]+red[2][3];
    }
  } else {
    // ---------------- kStage: 64m x 32k tile transpose ----------------
    int flat = b - 77;                     // 0..4198
    int bx = flat % NMT64, by = flat / NMT64;
    int m0 = bx*64, kg0 = by*32;
    __shared__ unsigned short Sh[32*66];   // [krow][m], stride 66 (2-way-free)
    __shared__ unsigned short Sl[32*66];
    __shared__ float ek[23];
    int t = threadIdx.x;
    if (t < 23) ek[t] = 0.f;
    __syncthreads();
    int krow = t >> 3, mseg = (t & 7) * 8;
    int kg = kg0 + krow;
    int mm = m0 + mseg;
    float kv[8], wv[8]; float sq = 0.f;
    #pragma unroll
    for (int i = 0; i < 8; i++) { kv[i] = 0.f; wv[i] = 0.f; }
    if (kg < KDIM) {
      const float* kr = K + (size_t)kg*M_TOT + mm;
      if (mm + 7 < M_TOT) {
        float4 a4 = *(const float4*)kr; float4 b4 = *(const float4*)(kr+4);
        kv[0]=a4.x; kv[1]=a4.y; kv[2]=a4.z; kv[3]=a4.w;
        kv[4]=b4.x; kv[5]=b4.y; kv[6]=b4.z; kv[7]=b4.w;
      } else {
        #pragma unroll
        for (int i = 0; i < 8; i++) if (mm+i < M_TOT) kv[i] = kr[i];
      }
      int j = kg / 17;
      // A values for m = mm..mm+7 span n0..n0+3 (4 loads + select)
      int nb = mm / 3;
      float av[4];
      #pragma unroll
      for (int i = 0; i < 4; i++)
        av[i] = (nb + i < NV) ? fmaxf(A[j*NV + nb + i], 0.f) : 0.f;
      #pragma unroll
      for (int i = 0; i < 8; i++) {
        float a = (mm+i < M_TOT) ? av[(mm+i)/3 - nb] : 0.f;
        wv[i] = kv[i]*a;
        sq = fmaf(kv[i], kv[i], sq);
      }
    }
    #pragma unroll
    for (int c = 0; c < 4; c++) {
      unsigned short h0 = f2bf(wv[2*c]),  h1 = f2bf(wv[2*c+1]);
      unsigned short l0 = f2bf(wv[2*c]   - bf2f(h0));
      unsigned short l1 = f2bf(wv[2*c+1] - bf2f(h1));
      *(unsigned*)&Sh[krow*66 + mseg + 2*c] = (unsigned)h0 | ((unsigned)h1 << 16);
      *(unsigned*)&Sl[krow*66 + mseg + 2*c] = (unsigned)l0 | ((unsigned)l1 << 16);
    }
    sq += __shfl_xor(sq, 1, 64);
    sq += __shfl_xor(sq, 2, 64);
    sq += __shfl_xor(sq, 4, 64);
    if ((t & 7) == 0 && kg < KDIM) atomicAdd(&ek[kg/17], sq);
    __syncthreads();
    int mrow = t >> 2, kq = t & 3;
    unsigned dh[4], dl[4];
    #pragma unroll
    for (int c2 = 0; c2 < 4; c2++) {
      unsigned short s0 = Sh[(kq*8 + 2*c2    )*66 + mrow];
      unsigned short s1 = Sh[(kq*8 + 2*c2 + 1)*66 + mrow];
      dh[c2] = (unsigned)s0 | ((unsigned)s1 << 16);
      unsigned short u0 = Sl[(kq*8 + 2*c2    )*66 + mrow];
      unsigned short u1 = Sl[(kq*8 + 2*c2 + 1)*66 + mrow];
      dl[c2] = (unsigned)u0 | ((unsigned)u1 << 16);
    }
    unsigned short* BtH = (unsigned short*)ws + BTH_OFF_U;
    unsigned short* BtL = (unsigned short*)ws + BTL_OFF_U;
    size_t o = (size_t)(m0 + mrow)*KPAD + kg0 + kq*8;
    *(u32x4*)(BtH + o) = (u32x4){dh[0], dh[1], dh[2], dh[3]};
    *(u32x4*)(BtL + o) = (u32x4){dl[0], dl[1], dl[2], dl[3]};
    if (t < 23) ws[EKP_OFF + t*NSTAGE + flat] = ek[t];
  }
}

// ---- kB: barrier-free, LDS-free split-bf16 MFMA GEMM, 2-deep pipelined.
//      Grid 646 (m-tile 32); block 256 = 4 waves, wave w owns p 64w..64w+63. ----
__global__ __launch_bounds__(256) void kB(float* __restrict__ ws) {
  const unsigned short* qbh = (const unsigned short*)ws + QBH_OFF_U;
  const unsigned short* qbl = (const unsigned short*)ws + QBL_OFF_U;
  const unsigned short* BtH = (const unsigned short*)ws + BTH_OFF_U;
  const unsigned short* BtL = (const unsigned short*)ws + BTL_OFF_U;
  float* __restrict__ TP = ws + TP_OFF;
  const int tid = threadIdx.x, bx = blockIdx.x;
  const int m0 = bx * 32;
  const int w = tid >> 6, lane = tid & 63;
  const int r = lane & 15, qd = lane >> 4;

  f32x4 acc[4][2];
  #pragma unroll
  for (int h = 0; h < 4; h++)
    #pragma unroll
    for (int f = 0; f < 2; f++) acc[h][f] = (f32x4){0.f,0.f,0.f,0.f};

  int aofs[4], bofs[2];
  #pragma unroll
  for (int h = 0; h < 4; h++) aofs[h] = (w*64 + h*16 + r)*KPAD + qd*8;
  #pragma unroll
  for (int f = 0; f < 2; f++) bofs[f] = (m0 + f*16 + r)*KPAD + qd*8;

  short8 ah[2][4], al[2][4], bh[2][2], bl[2][2];
  #pragma unroll
  for (int h = 0; h < 4; h++) {
    ah[0][h] = *(const short8*)(qbh + aofs[h]);
    al[0][h] = *(const short8*)(qbl + aofs[h]);
  }
  #pragma unroll
  for (int f = 0; f < 2; f++) {
    bh[0][f] = *(const short8*)(BtH + bofs[f]);
    bl[0][f] = *(const short8*)(BtL + bofs[f]);
  }
  #pragma unroll
  for (int ks = 0; ks < 13; ks++) {
    const int cur = ks & 1, nxt = cur ^ 1;
    if (ks + 1 < 13) {                      // prefetch ALL frags for ks+1
      const int o = (ks+1)*32;
      #pragma unroll
      for (int h = 0; h < 4; h++) {
        ah[nxt][h] = *(const short8*)(qbh + aofs[h] + o);
        al[nxt][h] = *(const short8*)(qbl + aofs[h] + o);
      }
      #pragma unroll
      for (int f = 0; f < 2; f++) {
        bh[nxt][f] = *(const short8*)(BtH + bofs[f] + o);
        bl[nxt][f] = *(const short8*)(BtL + bofs[f] + o);
      }
    }
    #pragma unroll
    for (int f = 0; f < 2; f++)
      #pragma unroll
      for (int h = 0; h < 4; h++) {
        acc[h][f] = __builtin_amdgcn_mfma_f32_16x16x32_bf16(ah[cur][h], bh[cur][f], acc[h][f], 0, 0, 0);
        acc[h][f] = __builtin_amdgcn_mfma_f32_16x16x32_bf16(ah[cur][h], bl[cur][f], acc[h][f], 0, 0, 0);
        acc[h][f] = __builtin_amdgcn_mfma_f32_16x16x32_bf16(al[cur][h], bh[cur][f], acc[h][f], 0, 0, 0);
      }
  }
  // C layout: col = lane&15 (m), row = qd*4 + g (p); skip pad rows p>=200
  #pragma unroll
  for (int h = 0; h < 4; h++)
    #pragma unroll
    for (int f = 0; f < 2; f++)
      #pragma unroll
      for (int g = 0; g < 4; g++) {
        int p = w*64 + h*16 + qd*4 + g;
        if (p < PREG)
          TP[(size_t)p*TP_STRIDE + m0 + f*16 + r] = acc[h][f][g];
      }
}

// ---- kC: skinning + verts + E_D. 1 vert/thread; G via wave-uniform pointer
//      (compiler -> s_load + SGPR-operand FMA: no LDS, scalar pipe). ----
__global__ __launch_bounds__(256) void kC(const float* __restrict__ V,
                                          const float* __restrict__ T,
                                          const float* __restrict__ Wp,
                                          const float* __restrict__ ws,
                                          float* __restrict__ out) {
  int p = blockIdx.y;
  int n = blockIdx.x*256 + threadIdx.x;
  const float* __restrict__ gp = ws + G_OFF + (size_t)p*288;   // uniform -> s_load
  __shared__ float tmp[4];
  float ed = 0.f;
  if (n < NV) {
    float wv[24]; float sum = 0.f;
    const float4* wp4 = (const float4*)(Wp + n*24);
    #pragma unroll
    for (int i = 0; i < 6; i++) {
      float4 v4 = wp4[i];
      wv[4*i+0] = fmaxf(v4.x, 0.f); wv[4*i+1] = fmaxf(v4.y, 0.f);
      wv[4*i+2] = fmaxf(v4.z, 0.f); wv[4*i+3] = fmaxf(v4.w, 0.f);
      sum += wv[4*i+0]+wv[4*i+1]+wv[4*i+2]+wv[4*i+3];
    }
    float inv = 1.f/(sum + 1e-8f);
    float M[12];
    #pragma unroll
    for (int i = 0; i < 12; i++) M[i] = 0.f;
    #pragma unroll
    for (int k = 0; k < 24; k++) {
      float wc = wv[k];
      #pragma unroll
      for (int i = 0; i < 12; i++)
        M[i] = fmaf(wc, gp[k*12 + i], M[i]);   // sgpr src0
    }
    #pragma unroll
    for (int i = 0; i < 12; i++) M[i] *= inv;
    size_t tb = (size_t)p*M_TOT + 3*n;
    size_t pb = (size_t)p*TP_STRIDE + 3*n;
    float t0 = ws[TP_OFF + pb + 0] + T[tb + 0];
    float t1 = ws[TP_OFF + pb + 1] + T[tb + 1];
    float t2 = ws[TP_OFF + pb + 2] + T[tb + 2];
    float v0 = M[0]*t0 + M[1]*t1 + M[2]*t2  + M[3];
    float v1 = M[4]*t0 + M[5]*t1 + M[6]*t2  + M[7];
    float v2 = M[8]*t0 + M[9]*t1 + M[10]*t2 + M[11];
    out[1+tb+0] = v0; out[1+tb+1] = v1; out[1+tb+2] = v2;
    float d0 = V[tb+0]-v0, d1 = V[tb+1]-v1, d2 = V[tb+2]-v2;
    ed = d0*d0 + d1*d1 + d2*d2;
  }
  ed = waveReduce(ed);
  int lane = threadIdx.x & 63, w = threadIdx.x >> 6;
  if (lane == 0) tmp[w] = ed;
  __syncthreads();
  if (threadIdx.x == 0)
    ((float*)ws)[EDP_OFF + blockIdx.y*27 + blockIdx.x] = tmp[0]+tmp[1]+tmp[2]+tmp[3];
}

// ---- kF1: parallel partial reductions (25 blocks) ----
__global__ __launch_bounds__(256) void kF1(float* __restrict__ ws) {
  __shared__ float sb[4];
  int b = blockIdx.x, t = threadIdx.x, lane = t & 63, w = t >> 6;
  if (b < 23) {
    float s = 0.f;
    for (int i = t; i < NSTAGE; i += 256) s += ws[EKP_OFF + b*NSTAGE + i];
    s = waveReduce(s);
    if (lane == 0) sb[w] = s;
    __syncthreads();
    if (t == 0) ws[RED_OFF + b] = sb[0]+sb[1]+sb[2]+sb[3];
  } else if (b == 23) {
    float s = 0.f;
    for (int i = t; i < 5400; i += 256) s += ws[EDP_OFF + i];
    s = waveReduce(s);
    if (lane == 0) sb[w] = s;
    __syncthreads();
    if (t == 0) ws[RED_OFF + 23] = sb[0]+sb[1]+sb[2]+sb[3];
  } else {
    if (w == 0) {
      float s = (lane < 27) ? ws[WIP_OFF + lane] : 0.f;
      s = waveReduce(s);
      if (lane == 0) ws[RED_OFF + 24] = s;
    } else if (w == 1) {
      float s = (lane < 27) ? ws[EWP_OFF + lane] : 0.f;
      s = waveReduce(s);
      if (lane == 0) ws[RED_OFF + 25] = s;
    } else if (w == 2) {
      float s = (lane < 27) ? ws[EAP_OFF + lane] : 0.f;
      s = waveReduce(s);
      if (lane == 0) ws[RED_OFF + 26] = s;
    }
  }
}

// ---- kF2: final combine ----
__global__ void kF2(const int* __restrict__ epoch, const float* __restrict__ ws,
                    float* __restrict__ out) {
  int t = threadIdx.x;
  float s = (t < 23) ? sqrtf(ws[RED_OFF + t]) : 0.f;
  s = waveReduce(s);
  if (t == 0) {
    float e    = (float)epoch[0];
    float g_wi = 0.1f   * expf(-0.1f  * e);
    float g_w  = 0.002f * expf(-0.008f* e);
    float g_a  = 0.001f * expf(-0.008f* e);
    float g_k  = 0.1f   * expf(-0.008f* e);
    out[0] = ws[RED_OFF+23] + g_wi*ws[RED_OFF+24] + g_w*ws[RED_OFF+25]
           + g_a*ws[RED_OFF+26] + g_k*s;
  }
}

extern "C" void kernel_launch(void* const* d_in, const int* in_sizes, int n_in,
                              void* d_out, int out_size, void* d_ws, size_t ws_size,
                              hipStream_t stream) {
  const float* V     = (const float*)d_in[0];
  const float* T     = (const float*)d_in[1];
  const float* J     = (const float*)d_in[2];
  const float* theta = (const float*)d_in[3];
  const float* Wp    = (const float*)d_in[4];
  const float* Wi    = (const float*)d_in[5];
  const float* A     = (const float*)d_in[6];
  const float* K     = (const float*)d_in[7];
  const float* b2    = (const float*)d_in[8];
  const int*   epoch = (const int*)d_in[9];
  float* out = (float*)d_out;
  float* ws  = (float*)d_ws;
  // needs ~54 MB workspace

  hipLaunchKernelGGL(kPre, dim3(77 + NSTAGE), dim3(256), 0, stream,
                     J, theta, b2, Wp, Wi, A, K, ws);
  hipLaunchKernelGGL(kB,   dim3(NMT32),       dim3(256), 0, stream, ws);
  hipLaunchKernelGGL(kC,   dim3(27, PREG),    dim3(256), 0, stream, V, T, Wp, ws, out);
  hipLaunchKernelGGL(kF1,  dim3(25),          dim3(256), 0, stream, ws);
  hipLaunchKernelGGL(kF2,  dim3(1),           dim3(64),  0, stream, epoch, ws, out);
}